// Round 2
// baseline (630.364 us; speedup 1.0000x reference)
//
#include <hip/hip_runtime.h>

#define NN 100000
#define NE 1600000

typedef float f4 __attribute__((ext_vector_type(4)));
typedef int i4 __attribute__((ext_vector_type(4)));

// ---------------- CSR build kernels ----------------

__global__ __launch_bounds__(256) void k_count(const i4* __restrict__ dst4,
                                               int* __restrict__ deg) {
    int t = blockIdx.x * blockDim.x + threadIdx.x;
    if (t < NE / 4) {
        i4 d = dst4[t];
        atomicAdd(&deg[d[0]], 1);
        atomicAdd(&deg[d[1]], 1);
        atomicAdd(&deg[d[2]], 1);
        atomicAdd(&deg[d[3]], 1);
    }
}

// Block scans 1024 elements (256 threads x 4 items). Exclusive prefix into
// offs, block total into bsums[b].
__global__ void k_scan1(const int* __restrict__ deg, int* __restrict__ offs,
                        int* __restrict__ bsums) {
    __shared__ int ts[256];
    int b = blockIdx.x, t = threadIdx.x;
    int base = b * 1024 + t * 4;
    int v[4];
    int s = 0;
#pragma unroll
    for (int i = 0; i < 4; ++i) {
        int idx = base + i;
        v[i] = (idx < NN) ? deg[idx] : 0;
        s += v[i];
    }
    ts[t] = s;
    __syncthreads();
    for (int off = 1; off < 256; off <<= 1) {
        int x = (t >= off) ? ts[t - off] : 0;
        __syncthreads();
        ts[t] += x;
        __syncthreads();
    }
    int excl = ts[t] - s;
#pragma unroll
    for (int i = 0; i < 4; ++i) {
        int idx = base + i;
        if (idx < NN) offs[idx] = excl;
        excl += v[i];
    }
    if (t == 255) bsums[b] = ts[255];
}

// wave-parallel scan of <=128 block sums (1 block, 64 threads)
__global__ void k_scan2(int* __restrict__ bsums, int nb) {
    int lane = threadIdx.x;
    int v0 = (lane < nb) ? bsums[lane] : 0;
    int v1 = (64 + lane < nb) ? bsums[64 + lane] : 0;
    int s0 = v0, s1 = v1;
    for (int o = 1; o < 64; o <<= 1) {
        int t0 = __shfl_up(s0, o, 64);
        int t1 = __shfl_up(s1, o, 64);
        if (lane >= o) { s0 += t0; s1 += t1; }
    }
    int tot0 = __shfl(s0, 63, 64);
    if (lane < nb) bsums[lane] = s0 - v0;
    if (64 + lane < nb) bsums[64 + lane] = tot0 + s1 - v1;
}

// fused: finalize offs, init cursor=offs, compute deg_inv
__global__ void k_scan3(int* __restrict__ offs, const int* __restrict__ bsums,
                        int* __restrict__ cursor, const int* __restrict__ deg,
                        float* __restrict__ dinv) {
    int i = blockIdx.x * blockDim.x + threadIdx.x;
    if (i < NN) {
        int o = offs[i] + bsums[i >> 10];
        offs[i] = o;
        cursor[i] = o;
        int dg = deg[i];
        dinv[i] = (dg > 0) ? (1.0f / (float)dg) : 0.0f;
        if (i == 0) offs[NN] = NE;
    }
}

__global__ __launch_bounds__(256) void k_scatter(const i4* __restrict__ src4,
                                                 const i4* __restrict__ dst4,
                                                 int* __restrict__ cursor,
                                                 int* __restrict__ ssrc) {
    int t = blockIdx.x * blockDim.x + threadIdx.x;
    if (t < NE / 4) {
        i4 s = src4[t];
        i4 d = dst4[t];
#pragma unroll
        for (int i = 0; i < 4; ++i) {
            int p = atomicAdd(&cursor[d[i]], 1);
            ssrc[p] = s[i];
        }
    }
}

// ---------------- fused SAGE layer ----------------
// One node per 64-lane wave. float4 per lane: fq = lane&7 is the feature
// quad, slot = lane>>3 is the edge slot (8 edges in flight; 2-deep unroll
// -> 16 independent cache lines outstanding per wave). Slot-reduce via
// shfl_xor(8/16/32), then 32x32 combine via wave broadcasts, weights in LDS.
template <int OUTF>
__global__ __launch_bounds__(256) void k_sage(
    const float* __restrict__ hin, const int* __restrict__ offs,
    const int* __restrict__ ssrc, const float* __restrict__ dinv,
    const float* __restrict__ Ws, const float* __restrict__ Wn,
    const float* __restrict__ bias, float* __restrict__ hout) {
    __shared__ float sWs[32 * OUTF];
    __shared__ float sWn[32 * OUTF];
    __shared__ float sB[OUTF];
    for (int i = threadIdx.x; i < 32 * OUTF; i += 256) {
        sWs[i] = Ws[i];
        sWn[i] = Wn[i];
    }
    if (threadIdx.x < OUTF) sB[threadIdx.x] = bias[threadIdx.x];
    __syncthreads();

    const int lane = threadIdx.x & 63;
    const int node = blockIdx.x * 4 + (threadIdx.x >> 6);
    const int fq = lane & 7;
    const int slot = lane >> 3;

    const int e0 = offs[node], e1 = offs[node + 1];
    const float di = dinv[node];
    f4 hs = *(const f4*)(hin + node * 32 + fq * 4);

    f4 acc = (f4)0.0f;
    int e = e0 + slot;
    for (; e + 8 < e1; e += 16) {
        int s0 = ssrc[e];
        int s1 = ssrc[e + 8];
        f4 v0 = *(const f4*)(hin + s0 * 32 + fq * 4);
        f4 v1 = *(const f4*)(hin + s1 * 32 + fq * 4);
        acc += v0 + v1;
    }
    if (e < e1) {
        int s0 = ssrc[e];
        acc += *(const f4*)(hin + s0 * 32 + fq * 4);
    }
#pragma unroll
    for (int m = 8; m <= 32; m <<= 1) {
#pragma unroll
        for (int c = 0; c < 4; ++c) acc[c] += __shfl_xor(acc[c], m, 64);
    }
    f4 hn = acc * di;

    const int j = lane & (OUTF - 1);
    float o = sB[j];
    float ha[4] = {hs[0], hs[1], hs[2], hs[3]};
    float na[4] = {hn[0], hn[1], hn[2], hn[3]};
#pragma unroll
    for (int k = 0; k < 32; ++k) {
        float a = __shfl(ha[k & 3], k >> 2, 64);
        float n = __shfl(na[k & 3], k >> 2, 64);
        o += a * sWs[k * OUTF + j] + n * sWn[k * OUTF + j];
    }
    if (lane < OUTF) hout[node * OUTF + j] = 1.0f / (1.0f + __expf(-o));
}

// ---------------- launcher ----------------

extern "C" void kernel_launch(void* const* d_in, const int* in_sizes, int n_in,
                              void* d_out, int out_size, void* d_ws, size_t ws_size,
                              hipStream_t stream) {
    const float* inputs = (const float*)d_in[0];
    const int* src = (const int*)d_in[1];
    const int* dst = (const int*)d_in[2];
    const float* Ws1 = (const float*)d_in[3];
    const float* Wn1 = (const float*)d_in[4];
    const float* b1 = (const float*)d_in[5];
    const float* Ws2 = (const float*)d_in[6];
    const float* Wn2 = (const float*)d_in[7];
    const float* b2 = (const float*)d_in[8];
    const float* Ws3 = (const float*)d_in[9];
    const float* Wn3 = (const float*)d_in[10];
    const float* b3 = (const float*)d_in[11];
    float* out = (float*)d_out;

    int* ws = (int*)d_ws;
    int* deg = ws;                         // 100000
    int* cursor = ws + 100000;             // 100000
    int* offs = ws + 200000;               // 100001
    int* bsums = ws + 300016;              // 128
    int* ssrc = ws + 300160;               // 1600000
    float* dinv = (float*)(ws + 1900160);  // 100000
    float* h1 = (float*)(ws + 2000160);    // 3200000
    float* h2 = (float*)(ws + 5200160);    // 3200000

    hipMemsetAsync(deg, 0, NN * sizeof(int), stream);

    const int egrid = (NE / 4 + 255) / 256;  // 1563
    k_count<<<egrid, 256, 0, stream>>>((const i4*)dst, deg);
    k_scan1<<<98, 256, 0, stream>>>(deg, offs, bsums);
    k_scan2<<<1, 64, 0, stream>>>(bsums, 98);
    k_scan3<<<(NN + 255) / 256, 256, 0, stream>>>(offs, bsums, cursor, deg, dinv);
    k_scatter<<<egrid, 256, 0, stream>>>((const i4*)src, (const i4*)dst, cursor, ssrc);

    k_sage<32><<<NN / 4, 256, 0, stream>>>(inputs, offs, ssrc, dinv, Ws1, Wn1, b1, h1);
    k_sage<32><<<NN / 4, 256, 0, stream>>>(h1, offs, ssrc, dinv, Ws2, Wn2, b2, h2);
    k_sage<16><<<NN / 4, 256, 0, stream>>>(h2, offs, ssrc, dinv, Ws3, Wn3, b3, out);
}

// Round 3
// 392.689 us; speedup vs baseline: 1.6053x; 1.6053x over previous
//
#include <hip/hip_runtime.h>

#define NN 100000
#define NE 1600000

typedef float f4 __attribute__((ext_vector_type(4)));
typedef int i4 __attribute__((ext_vector_type(4)));
typedef unsigned short us4 __attribute__((ext_vector_type(4)));

__device__ __forceinline__ float bf2f(unsigned short v) {
    return __builtin_bit_cast(float, ((unsigned)v) << 16);
}
__device__ __forceinline__ unsigned short f2bf(float f) {
    unsigned u = __builtin_bit_cast(unsigned, f);
    return (unsigned short)((u + 0x7FFF + ((u >> 16) & 1)) >> 16);
}

// ---------------- input -> bf16 gather table ----------------
__global__ __launch_bounds__(256) void k_convert(const f4* __restrict__ in4,
                                                 us4* __restrict__ out4) {
    int t = blockIdx.x * blockDim.x + threadIdx.x;  // 800000 threads
    if (t < NN * 32 / 4) {
        f4 v = in4[t];
        us4 o;
#pragma unroll
        for (int c = 0; c < 4; ++c) o[c] = f2bf(v[c]);
        out4[t] = o;
    }
}

// ---------------- CSR build ----------------
// count degrees AND capture each edge's rank within its dst (atomic return).
__global__ __launch_bounds__(256) void k_count(const i4* __restrict__ dst4,
                                               int* __restrict__ deg,
                                               us4* __restrict__ rank4) {
    int t = blockIdx.x * blockDim.x + threadIdx.x;
    if (t < NE / 4) {
        i4 d = dst4[t];
        us4 r;
#pragma unroll
        for (int i = 0; i < 4; ++i) r[i] = (unsigned short)atomicAdd(&deg[d[i]], 1);
        rank4[t] = r;
    }
}

__global__ void k_scan1(const int* __restrict__ deg, int* __restrict__ offs,
                        int* __restrict__ bsums) {
    __shared__ int ts[256];
    int b = blockIdx.x, t = threadIdx.x;
    int base = b * 1024 + t * 4;
    int v[4];
    int s = 0;
#pragma unroll
    for (int i = 0; i < 4; ++i) {
        int idx = base + i;
        v[i] = (idx < NN) ? deg[idx] : 0;
        s += v[i];
    }
    ts[t] = s;
    __syncthreads();
    for (int off = 1; off < 256; off <<= 1) {
        int x = (t >= off) ? ts[t - off] : 0;
        __syncthreads();
        ts[t] += x;
        __syncthreads();
    }
    int excl = ts[t] - s;
#pragma unroll
    for (int i = 0; i < 4; ++i) {
        int idx = base + i;
        if (idx < NN) offs[idx] = excl;
        excl += v[i];
    }
    if (t == 255) bsums[b] = ts[255];
}

__global__ void k_scan2(int* __restrict__ bsums, int nb) {
    int lane = threadIdx.x;
    int v0 = (lane < nb) ? bsums[lane] : 0;
    int v1 = (64 + lane < nb) ? bsums[64 + lane] : 0;
    int s0 = v0, s1 = v1;
    for (int o = 1; o < 64; o <<= 1) {
        int t0 = __shfl_up(s0, o, 64);
        int t1 = __shfl_up(s1, o, 64);
        if (lane >= o) { s0 += t0; s1 += t1; }
    }
    int tot0 = __shfl(s0, 63, 64);
    if (lane < nb) bsums[lane] = s0 - v0;
    if (64 + lane < nb) bsums[64 + lane] = tot0 + s1 - v1;
}

// finalize offs; deg_inv written IN PLACE over deg (deg dead afterwards)
__global__ void k_scan3(int* __restrict__ offs, const int* __restrict__ bsums,
                        int* __restrict__ deg, float* __restrict__ dinv) {
    int i = blockIdx.x * blockDim.x + threadIdx.x;
    if (i < NN) {
        offs[i] += bsums[i >> 10];
        int dg = deg[i];
        dinv[i] = (dg > 0) ? (1.0f / (float)dg) : 0.0f;
        if (i == 0) offs[NN] = NE;
    }
}

// atomic-free scatter: position = offs[dst] + rank
__global__ __launch_bounds__(256) void k_scatter(const i4* __restrict__ src4,
                                                 const i4* __restrict__ dst4,
                                                 const us4* __restrict__ rank4,
                                                 const int* __restrict__ offs,
                                                 int* __restrict__ ssrc) {
    int t = blockIdx.x * blockDim.x + threadIdx.x;
    if (t < NE / 4) {
        i4 s = src4[t];
        i4 d = dst4[t];
        us4 r = rank4[t];
#pragma unroll
        for (int i = 0; i < 4; ++i) ssrc[offs[d[i]] + (int)r[i]] = s[i];
    }
}

// ---------------- fused SAGE layer (persistent, bf16 gather) ----------------
// One node per wave, grid-stride. Gather table bf16: one 64B line per row.
// fq = lane&7 feature quad, slot = lane>>3 edge slot (8 edges, 2-deep unroll).
// Combine split across halves: lanes<32 self-part, lanes>=32 neigh-part,
// each 32 bpermute+fma, then one shfl_xor(32) add.
template <int OUTF, bool WG>
__global__ __launch_bounds__(256) void k_sage(
    const float* __restrict__ hin, const unsigned short* __restrict__ gt,
    const int* __restrict__ offs, const int* __restrict__ ssrc,
    const float* __restrict__ dinv,
    const float* __restrict__ Ws, const float* __restrict__ Wn,
    const float* __restrict__ bias,
    float* __restrict__ hout, unsigned short* __restrict__ gout) {
    __shared__ float sW[2][32 * OUTF];
    __shared__ float sB[OUTF];
    for (int i = threadIdx.x; i < 32 * OUTF; i += 256) {
        sW[0][i] = Ws[i];
        sW[1][i] = Wn[i];
    }
    if (threadIdx.x < OUTF) sB[threadIdx.x] = bias[threadIdx.x];
    __syncthreads();

    const int lane = threadIdx.x & 63;
    const int fq = lane & 7;
    const int slot = lane >> 3;
    const int half = lane >> 5;  // 0=self, 1=neigh
    const float* wt = sW[half];
    const int j = lane & (OUTF - 1);
    const int stride = gridDim.x * 4;

    for (int node = blockIdx.x * 4 + (threadIdx.x >> 6); node < NN; node += stride) {
        const int e0 = offs[node], e1 = offs[node + 1];
        f4 acc = (f4)0.0f;
        int e = e0 + slot;
        for (; e + 8 < e1; e += 16) {
            int s0 = ssrc[e];
            int s1 = ssrc[e + 8];
            us4 a = *(const us4*)(gt + s0 * 32 + fq * 4);
            us4 b = *(const us4*)(gt + s1 * 32 + fq * 4);
#pragma unroll
            for (int c = 0; c < 4; ++c) acc[c] += bf2f(a[c]) + bf2f(b[c]);
        }
        if (e < e1) {
            int s0 = ssrc[e];
            us4 a = *(const us4*)(gt + s0 * 32 + fq * 4);
#pragma unroll
            for (int c = 0; c < 4; ++c) acc[c] += bf2f(a[c]);
        }
#pragma unroll
        for (int m = 8; m <= 32; m <<= 1) {
#pragma unroll
            for (int c = 0; c < 4; ++c) acc[c] += __shfl_xor(acc[c], m, 64);
        }
        const float di = dinv[node];
        f4 hs = *(const f4*)(hin + node * 32 + fq * 4);
        float x[4];
#pragma unroll
        for (int c = 0; c < 4; ++c) x[c] = half ? acc[c] * di : hs[c];
        float o = half ? 0.0f : sB[j];
#pragma unroll
        for (int k = 0; k < 32; ++k) {
            float v = __shfl(x[k & 3], (half << 5) + (k >> 2), 64);
            o += v * wt[k * OUTF + j];
        }
        o += __shfl_xor(o, 32, 64);
        if (lane < OUTF) {
            float s = 1.0f / (1.0f + __expf(-o));
            hout[node * OUTF + j] = s;
            if (WG) gout[node * OUTF + j] = f2bf(s);
        }
    }
}

// ---------------- launcher ----------------

extern "C" void kernel_launch(void* const* d_in, const int* in_sizes, int n_in,
                              void* d_out, int out_size, void* d_ws, size_t ws_size,
                              hipStream_t stream) {
    const float* inputs = (const float*)d_in[0];
    const int* src = (const int*)d_in[1];
    const int* dst = (const int*)d_in[2];
    const float* Ws1 = (const float*)d_in[3];
    const float* Wn1 = (const float*)d_in[4];
    const float* b1 = (const float*)d_in[5];
    const float* Ws2 = (const float*)d_in[6];
    const float* Wn2 = (const float*)d_in[7];
    const float* b2 = (const float*)d_in[8];
    const float* Ws3 = (const float*)d_in[9];
    const float* Wn3 = (const float*)d_in[10];
    const float* b3 = (const float*)d_in[11];
    float* out = (float*)d_out;

    int* ws = (int*)d_ws;
    int* deg = ws;                          // 100000 (dinv aliases after scan3)
    float* dinv = (float*)ws;
    int* offs = ws + 100000;                // 100001
    int* bsums = ws + 200016;               // 128
    int* ssrc = ws + 200160;                // 1600000
    float* hf = (float*)(ws + 1800160);     // 3200000 floats (in-place h)
    unsigned short* gA = (unsigned short*)(ws + 5000160);  // 3.2M ushort
    unsigned short* gB = (unsigned short*)(ws + 6600160);  // 3.2M ushort
    unsigned short* rank = gB;              // rank (0.8M ints) dies before gB live

    hipMemsetAsync(deg, 0, NN * sizeof(int), stream);

    k_convert<<<3125, 256, 0, stream>>>((const f4*)inputs, (us4*)gA);
    const int egrid = (NE / 4 + 255) / 256;
    k_count<<<egrid, 256, 0, stream>>>((const i4*)dst, deg, (us4*)rank);
    k_scan1<<<98, 256, 0, stream>>>(deg, offs, bsums);
    k_scan2<<<1, 64, 0, stream>>>(bsums, 98);
    k_scan3<<<(NN + 255) / 256, 256, 0, stream>>>(offs, bsums, deg, dinv);
    k_scatter<<<egrid, 256, 0, stream>>>((const i4*)src, (const i4*)dst,
                                         (const us4*)rank, offs, ssrc);

    // layer1: self from fp32 inputs, gather from bf16(inputs)=gA, out hf + gB
    k_sage<32, true><<<2048, 256, 0, stream>>>(inputs, gA, offs, ssrc, dinv,
                                               Ws1, Wn1, b1, hf, gB);
    // layer2: self hf (in-place ok), gather gB, out hf + gA
    k_sage<32, true><<<2048, 256, 0, stream>>>(hf, gB, offs, ssrc, dinv,
                                               Ws2, Wn2, b2, hf, gA);
    // layer3: self hf, gather gA, out d_out (fp32), no table
    k_sage<16, false><<<2048, 256, 0, stream>>>(hf, gA, offs, ssrc, dinv,
                                                Ws3, Wn3, b3, out, nullptr);
}